// Round 1
// baseline (127.380 us; speedup 1.0000x reference)
//
#include <hip/hip_runtime.h>

// SoftFAPELoss: B=8, N=M=4096, D=3.
// Single fused kernel: transform X_true into LDS (SoA), each thread-group of
// 8 lanes handles one query row n with a strided-float4 partition of M.
// Two passes: (1) row min distance, (2) exp2-based softmax-weighted sum.
// Row reduction fully in-wave (lane = row*8 + chunk). Scalar output via
// one atomicAdd per block.

#define B_    8
#define N_    4096
#define M_    4096
#define BLOCK 256
#define G_    8              // lanes per row
#define ROWS  (BLOCK / G_)   // 32 rows per block

__global__ __launch_bounds__(BLOCK) void softfape_kernel(
    const float* __restrict__ X_pred,      // (B,N,3)
    const float* __restrict__ X_true,      // (B,M,3)
    const float* __restrict__ R_pred,      // (B,3,3)
    const float* __restrict__ t_pred,      // (B,3)
    const float* __restrict__ R_true,      // (B,3,3)
    const float* __restrict__ t_true,      // (B,3)
    const float* __restrict__ temperature, // scalar
    float* __restrict__ out)               // scalar
{
    __shared__ __align__(16) float xs[M_];
    __shared__ __align__(16) float ys[M_];
    __shared__ __align__(16) float zs[M_];
    __shared__ float row_wd[ROWS];

    const int b   = blockIdx.y;
    const int tid = threadIdx.x;

    // ---- stage Xt = R_true @ x + t_true into LDS (SoA) ----
    {
        const float r00 = R_true[b*9+0], r01 = R_true[b*9+1], r02 = R_true[b*9+2];
        const float r10 = R_true[b*9+3], r11 = R_true[b*9+4], r12 = R_true[b*9+5];
        const float r20 = R_true[b*9+6], r21 = R_true[b*9+7], r22 = R_true[b*9+8];
        const float t0 = t_true[b*3+0], t1 = t_true[b*3+1], t2 = t_true[b*3+2];
        for (int m = tid; m < M_; m += BLOCK) {
            const size_t base = ((size_t)b * M_ + m) * 3;
            const float x = X_true[base + 0];
            const float y = X_true[base + 1];
            const float z = X_true[base + 2];
            xs[m] = fmaf(r00, x, fmaf(r01, y, fmaf(r02, z, t0)));
            ys[m] = fmaf(r10, x, fmaf(r11, y, fmaf(r12, z, t1)));
            zs[m] = fmaf(r20, x, fmaf(r21, y, fmaf(r22, z, t2)));
        }
    }
    __syncthreads();

    const int lrow = tid >> 3;   // 0..31
    const int g    = tid & 7;    // 0..7  (chunk lane within row)
    const int n    = blockIdx.x * ROWS + lrow;

    // ---- my transformed query point Xp[b,n] (redundant across the 8 g-lanes) ----
    float p0, p1, p2;
    {
        const size_t base = ((size_t)b * N_ + n) * 3;
        const float x = X_pred[base + 0];
        const float y = X_pred[base + 1];
        const float z = X_pred[base + 2];
        p0 = fmaf(R_pred[b*9+0], x, fmaf(R_pred[b*9+1], y, fmaf(R_pred[b*9+2], z, t_pred[b*3+0])));
        p1 = fmaf(R_pred[b*9+3], x, fmaf(R_pred[b*9+4], y, fmaf(R_pred[b*9+5], z, t_pred[b*3+1])));
        p2 = fmaf(R_pred[b*9+6], x, fmaf(R_pred[b*9+7], y, fmaf(R_pred[b*9+8], z, t_pred[b*3+2])));
    }

    // ---- pass 1: min distance over my strided-float4 subset of M ----
    float dmin = 3.4e38f;
    #pragma unroll 2
    for (int k = 0; k < M_ / (4 * G_); ++k) {
        const int base = k * (4 * G_) + g * 4;
        const float4 xv = *(const float4*)&xs[base];
        const float4 yv = *(const float4*)&ys[base];
        const float4 zv = *(const float4*)&zs[base];
        {
            const float dx = xv.x - p0, dy = yv.x - p1, dz = zv.x - p2;
            dmin = fminf(dmin, fmaf(dx, dx, fmaf(dy, dy, dz * dz)));
        }
        {
            const float dx = xv.y - p0, dy = yv.y - p1, dz = zv.y - p2;
            dmin = fminf(dmin, fmaf(dx, dx, fmaf(dy, dy, dz * dz)));
        }
        {
            const float dx = xv.z - p0, dy = yv.z - p1, dz = zv.z - p2;
            dmin = fminf(dmin, fmaf(dx, dx, fmaf(dy, dy, dz * dz)));
        }
        {
            const float dx = xv.w - p0, dy = yv.w - p1, dz = zv.w - p2;
            dmin = fminf(dmin, fmaf(dx, dx, fmaf(dy, dy, dz * dz)));
        }
    }
    // reduce min across the 8 chunk-lanes of this row (stay within row group)
    dmin = fminf(dmin, __shfl_xor(dmin, 1));
    dmin = fminf(dmin, __shfl_xor(dmin, 2));
    dmin = fminf(dmin, __shfl_xor(dmin, 4));

    // ---- pass 2: softmax-weighted distance, shifted by dmin ----
    const float T     = temperature[0];
    const float sc    = 1.4426950408889634f / T;  // log2(e)/T
    const float negsc = -sc;
    const float barg  = dmin * sc;

    float lsum = 0.0f, ssum = 0.0f;
    #pragma unroll 2
    for (int k = 0; k < M_ / (4 * G_); ++k) {
        const int base = k * (4 * G_) + g * 4;
        const float4 xv = *(const float4*)&xs[base];
        const float4 yv = *(const float4*)&ys[base];
        const float4 zv = *(const float4*)&zs[base];
        {
            const float dx = xv.x - p0, dy = yv.x - p1, dz = zv.x - p2;
            const float d = fmaf(dx, dx, fmaf(dy, dy, dz * dz));
            const float w = __builtin_amdgcn_exp2f(fmaf(d, negsc, barg));
            lsum += w;
            ssum = fmaf(w, d, ssum);
        }
        {
            const float dx = xv.y - p0, dy = yv.y - p1, dz = zv.y - p2;
            const float d = fmaf(dx, dx, fmaf(dy, dy, dz * dz));
            const float w = __builtin_amdgcn_exp2f(fmaf(d, negsc, barg));
            lsum += w;
            ssum = fmaf(w, d, ssum);
        }
        {
            const float dx = xv.z - p0, dy = yv.z - p1, dz = zv.z - p2;
            const float d = fmaf(dx, dx, fmaf(dy, dy, dz * dz));
            const float w = __builtin_amdgcn_exp2f(fmaf(d, negsc, barg));
            lsum += w;
            ssum = fmaf(w, d, ssum);
        }
        {
            const float dx = xv.w - p0, dy = yv.w - p1, dz = zv.w - p2;
            const float d = fmaf(dx, dx, fmaf(dy, dy, dz * dz));
            const float w = __builtin_amdgcn_exp2f(fmaf(d, negsc, barg));
            lsum += w;
            ssum = fmaf(w, d, ssum);
        }
    }

    // reduce (lsum, ssum) across the 8 chunk-lanes of this row
    lsum += __shfl_xor(lsum, 1);  ssum += __shfl_xor(ssum, 1);
    lsum += __shfl_xor(lsum, 2);  ssum += __shfl_xor(ssum, 2);
    lsum += __shfl_xor(lsum, 4);  ssum += __shfl_xor(ssum, 4);

    if (g == 0) row_wd[lrow] = ssum / lsum;
    __syncthreads();

    // ---- block reduction of 32 row results, one atomic per block ----
    if (tid < 64) {
        float v = (tid < ROWS) ? row_wd[tid] : 0.0f;
        v += __shfl_xor(v, 1);
        v += __shfl_xor(v, 2);
        v += __shfl_xor(v, 4);
        v += __shfl_xor(v, 8);
        v += __shfl_xor(v, 16);
        if (tid == 0) atomicAdd(out, v * (1.0f / ((float)B_ * (float)N_)));
    }
}

extern "C" void kernel_launch(void* const* d_in, const int* in_sizes, int n_in,
                              void* d_out, int out_size, void* d_ws, size_t ws_size,
                              hipStream_t stream) {
    const float* X_pred = (const float*)d_in[0];
    const float* X_true = (const float*)d_in[1];
    const float* R_pred = (const float*)d_in[2];
    const float* t_pred = (const float*)d_in[3];
    const float* R_true = (const float*)d_in[4];
    const float* t_true = (const float*)d_in[5];
    const float* temp   = (const float*)d_in[6];
    float* out = (float*)d_out;

    hipMemsetAsync(out, 0, sizeof(float), stream);

    dim3 grid(N_ / ROWS, B_);
    softfape_kernel<<<grid, BLOCK, 0, stream>>>(
        X_pred, X_true, R_pred, t_pred, R_true, t_true, temp, out);
}